// Round 1
// baseline (291.658 us; speedup 1.0000x reference)
//
#include <hip/hip_runtime.h>

typedef __attribute__((ext_vector_type(8))) _Float16 f16x8;
typedef __attribute__((ext_vector_type(4))) float f32x4;

#define B_SZ   16
#define N_SEQ  4096
#define M_CTX  77
#define M_PAD  96
#define NH     8

__device__ __forceinline__ _Float16 f2h(float x) { return (_Float16)x; }

// ---------------------------------------------------------------------------
// prep: W [K][512] fp32  ->  WT [512][K] f16   (LDS-tiled transpose)
// grid (16, 24, 4): z selects matrix; block 256
// ---------------------------------------------------------------------------
__global__ __launch_bounds__(256)
void prep(const float* __restrict__ Wq, const float* __restrict__ Wk,
          const float* __restrict__ Wv, const float* __restrict__ Wo,
          _Float16* __restrict__ WqT, _Float16* __restrict__ WkT,
          _Float16* __restrict__ WvT, _Float16* __restrict__ WoT)
{
    __shared__ float t[32][33];
    const float* W; _Float16* WT; int K;
    switch (blockIdx.z) {
        case 0:  W = Wq; WT = WqT; K = 512; break;
        case 1:  W = Wk; WT = WkT; K = 768; break;
        case 2:  W = Wv; WT = WvT; K = 768; break;
        default: W = Wo; WT = WoT; K = 512; break;
    }
    const int ky = blockIdx.y;
    if (ky * 32 >= K) return;
    const int nx = blockIdx.x;
    const int tr = threadIdx.x >> 5, tc = threadIdx.x & 31;
#pragma unroll
    for (int i = 0; i < 4; ++i) {
        int kr = tr + i * 8;
        t[kr][tc] = W[(size_t)(ky * 32 + kr) * 512 + nx * 32 + tc];
    }
    __syncthreads();
#pragma unroll
    for (int i = 0; i < 4; ++i) {
        int nr = tr + i * 8;
        WT[(size_t)(nx * 32 + nr) * K + ky * 32 + tc] = f2h(t[tc][nr]);
    }
}

// ---------------------------------------------------------------------------
// kv_proj: K[b,h,m,d] (m padded to 96 w/ zeros) and V transposed [b,h,d,m]
// grid (8 h, 16 b, 2 kv); block 256 = 4 waves, wave w -> d-cols [w*16, w*16+16)
// ---------------------------------------------------------------------------
__global__ __launch_bounds__(256)
void kv_proj(const float* __restrict__ cond, const _Float16* __restrict__ WkT,
             const _Float16* __restrict__ WvT, _Float16* __restrict__ Kp,
             _Float16* __restrict__ Vt)
{
    const int tid = threadIdx.x;
    const int l = tid & 63, w = tid >> 6;
    const int lrow = l & 15, lk = l >> 4;
    const int h = blockIdx.x, b = blockIdx.y, which = blockIdx.z;
    const _Float16* WT = which ? WvT : WkT;
    const float* cb = cond + (size_t)b * M_CTX * 768;

    f32x4 acc[5];
#pragma unroll
    for (int i = 0; i < 5; ++i)
#pragma unroll
        for (int e = 0; e < 4; ++e) acc[i][e] = 0.f;

    const int n = h * 64 + w * 16 + lrow;
    for (int kk = 0; kk < 24; ++kk) {
        f16x8 bfrag = *(const f16x8*)(WT + (size_t)n * 768 + kk * 32 + lk * 8);
#pragma unroll
        for (int rt = 0; rt < 5; ++rt) {
            int m = rt * 16 + lrow;
            f16x8 afrag;
#pragma unroll
            for (int j = 0; j < 8; ++j) afrag[j] = (_Float16)0.f;
            if (m < M_CTX) {
                const float* a = cb + (size_t)m * 768 + kk * 32 + lk * 8;
                float4 f0 = *(const float4*)a;
                float4 f1 = *(const float4*)(a + 4);
                afrag[0] = f2h(f0.x); afrag[1] = f2h(f0.y);
                afrag[2] = f2h(f0.z); afrag[3] = f2h(f0.w);
                afrag[4] = f2h(f1.x); afrag[5] = f2h(f1.y);
                afrag[6] = f2h(f1.z); afrag[7] = f2h(f1.w);
            }
            acc[rt] = __builtin_amdgcn_mfma_f32_16x16x32_f16(afrag, bfrag, acc[rt], 0, 0, 0);
        }
    }

    const int bh = b * NH + h;
    const int d = w * 16 + lrow;
    if (which == 0) {
#pragma unroll
        for (int rt = 0; rt < 5; ++rt)
#pragma unroll
            for (int r = 0; r < 4; ++r) {
                int m = rt * 16 + lk * 4 + r;
                Kp[((size_t)bh * M_PAD + m) * 64 + d] = f2h(acc[rt][r]);
            }
#pragma unroll
        for (int r = 0; r < 4; ++r) {
            int m = 80 + lk * 4 + r;
            Kp[((size_t)bh * M_PAD + m) * 64 + d] = (_Float16)0.f;
        }
    } else {
#pragma unroll
        for (int rt = 0; rt < 5; ++rt)
#pragma unroll
            for (int r = 0; r < 4; ++r) {
                int m = rt * 16 + lk * 4 + r;
                Vt[((size_t)bh * 64 + d) * M_PAD + m] = f2h(acc[rt][r]);
            }
#pragma unroll
        for (int r = 0; r < 4; ++r) {
            int m = 80 + lk * 4 + r;
            Vt[((size_t)bh * 64 + d) * M_PAD + m] = (_Float16)0.f;
        }
    }
}

// ---------------------------------------------------------------------------
// gemm512: C[M][512] = A[M][512] @ B (B given transposed f16 BT[512][512])
// MODE 0: A fp32, C f16 (scaled)      -- Q projection
// MODE 1: A f16,  C fp32 (+bias)      -- O projection
// grid: 2048 1-D blocks, XCD-chunked swizzle so a row-block's 4 col-blocks
// share one XCD's L2. block 256 = 4 waves (2x2 of 64x64).
// ---------------------------------------------------------------------------
template<int MODE>
__global__ __launch_bounds__(256)
void gemm512(const void* __restrict__ Av, const _Float16* __restrict__ BT,
             void* __restrict__ Cv, const float* __restrict__ bias, float scale)
{
    __shared__ _Float16 As[128][64];
    __shared__ _Float16 Bs[128][64];

    const int bid = blockIdx.x;
    const int rb = (bid & 7) + 8 * (bid >> 5);   // row block 0..511
    const int cb = (bid >> 3) & 3;               // col block 0..3
    const size_t row0 = (size_t)rb * 128;
    const int col0 = cb * 128;

    const int tid = threadIdx.x;
    const int l = tid & 63;
    const int wid = tid >> 6;
    const int wy = wid >> 1, wx = wid & 1;
    const int lrow = l & 15, lk = l >> 4;

    f32x4 acc[4][4];
#pragma unroll
    for (int i = 0; i < 4; ++i)
#pragma unroll
        for (int j = 0; j < 4; ++j)
#pragma unroll
            for (int e = 0; e < 4; ++e) acc[i][j][e] = 0.f;

    const int srow = tid >> 1;   // 0..127
    const int skh = tid & 1;     // 0..1

    for (int kt = 0; kt < 8; ++kt) {
        __syncthreads();
        // ---- stage A tile [128][64] (XOR slot swizzle: slot ^= row&7) ----
        if (MODE == 0) {
            const float* asrc = (const float*)Av + (row0 + srow) * 512 + kt * 64 + skh * 32;
#pragma unroll
            for (int j = 0; j < 4; ++j) {
                float4 f0 = *(const float4*)(asrc + j * 8);
                float4 f1 = *(const float4*)(asrc + j * 8 + 4);
                f16x8 pk;
                pk[0] = f2h(f0.x); pk[1] = f2h(f0.y); pk[2] = f2h(f0.z); pk[3] = f2h(f0.w);
                pk[4] = f2h(f1.x); pk[5] = f2h(f1.y); pk[6] = f2h(f1.z); pk[7] = f2h(f1.w);
                int slot = (skh * 4 + j) ^ (srow & 7);
                *(f16x8*)&As[srow][slot * 8] = pk;
            }
        } else {
            const _Float16* asrc = (const _Float16*)Av + (row0 + srow) * 512 + kt * 64 + skh * 32;
#pragma unroll
            for (int j = 0; j < 4; ++j) {
                f16x8 pk = *(const f16x8*)(asrc + j * 8);
                int slot = (skh * 4 + j) ^ (srow & 7);
                *(f16x8*)&As[srow][slot * 8] = pk;
            }
        }
        // ---- stage B tile ----
        {
            const _Float16* bsrc = BT + (size_t)(col0 + srow) * 512 + kt * 64 + skh * 32;
#pragma unroll
            for (int j = 0; j < 4; ++j) {
                f16x8 pk = *(const f16x8*)(bsrc + j * 8);
                int slot = (skh * 4 + j) ^ (srow & 7);
                *(f16x8*)&Bs[srow][slot * 8] = pk;
            }
        }
        __syncthreads();
        // ---- MFMA over the two 32-k halves ----
#pragma unroll
        for (int kk = 0; kk < 2; ++kk) {
            f16x8 af[4], bf[4];
#pragma unroll
            for (int mt = 0; mt < 4; ++mt) {
                int r = wy * 64 + mt * 16 + lrow;
                int slot = (kk * 4 + lk) ^ (r & 7);
                af[mt] = *(const f16x8*)&As[r][slot * 8];
            }
#pragma unroll
            for (int nt = 0; nt < 4; ++nt) {
                int r = wx * 64 + nt * 16 + lrow;
                int slot = (kk * 4 + lk) ^ (r & 7);
                bf[nt] = *(const f16x8*)&Bs[r][slot * 8];
            }
#pragma unroll
            for (int mt = 0; mt < 4; ++mt)
#pragma unroll
                for (int nt = 0; nt < 4; ++nt)
                    acc[mt][nt] = __builtin_amdgcn_mfma_f32_16x16x32_f16(af[mt], bf[nt], acc[mt][nt], 0, 0, 0);
        }
    }

    // ---- epilogue ----
#pragma unroll
    for (int mt = 0; mt < 4; ++mt)
#pragma unroll
        for (int nt = 0; nt < 4; ++nt)
#pragma unroll
            for (int r = 0; r < 4; ++r) {
                size_t row = row0 + wy * 64 + mt * 16 + lk * 4 + r;
                int col = col0 + wx * 64 + nt * 16 + lrow;
                float v = acc[mt][nt][r];
                if (MODE == 0) {
                    ((_Float16*)Cv)[row * 512 + col] = f2h(v * scale);
                } else {
                    ((float*)Cv)[row * 512 + col] = v + bias[col];
                }
            }
}

// ---------------------------------------------------------------------------
// attn: per (b, 64-row tile): for each head: S=QK^T, softmax (cols 77..79
// masked), P@V. AO aliases Q (same rows/cols read-before-write per wave).
// grid (64 tiles, 16 b); block 256 = 4 waves, wave = 16 Q rows.
// ---------------------------------------------------------------------------
__global__ __launch_bounds__(256)
void attn(const _Float16* __restrict__ Q, const _Float16* __restrict__ Kp,
          const _Float16* __restrict__ Vt, _Float16* __restrict__ AO)
{
    __shared__ _Float16 Pl[4][16][104];   // stride 104 -> 16B aligned, 2-way banks
    const int tid = threadIdx.x;
    const int l = tid & 63, w = tid >> 6;
    const int lrow = l & 15, lk = l >> 4;
    const int b = blockIdx.y, tile = blockIdx.x;
    const size_t rowbase = (size_t)b * N_SEQ + tile * 64 + w * 16;

    // zero the pad columns 80..95 of this wave's P region (cols 77..79 get
    // masked writes each head; 80..95 are only ever written here)
    for (int idx = l; idx < 256; idx += 64)
        Pl[w][idx >> 4][80 + (idx & 15)] = (_Float16)0.f;

    for (int h = 0; h < NH; ++h) {
        const size_t qoff = (rowbase + lrow) * 512 + h * 64;
        f16x8 qf0 = *(const f16x8*)(Q + qoff + lk * 8);
        f16x8 qf1 = *(const f16x8*)(Q + qoff + 32 + lk * 8);

        const _Float16* Kb = Kp + (size_t)(b * NH + h) * M_PAD * 64;
        f32x4 s[5];
#pragma unroll
        for (int i = 0; i < 5; ++i)
#pragma unroll
            for (int e = 0; e < 4; ++e) s[i][e] = 0.f;

#pragma unroll
        for (int ct = 0; ct < 5; ++ct) {
            f16x8 kf0 = *(const f16x8*)(Kb + (size_t)(ct * 16 + lrow) * 64 + lk * 8);
            f16x8 kf1 = *(const f16x8*)(Kb + (size_t)(ct * 16 + lrow) * 64 + 32 + lk * 8);
            s[ct] = __builtin_amdgcn_mfma_f32_16x16x32_f16(qf0, kf0, s[ct], 0, 0, 0);
            s[ct] = __builtin_amdgcn_mfma_f32_16x16x32_f16(qf1, kf1, s[ct], 0, 0, 0);
        }

        // softmax over 77 cols, rows lk*4+r, cols spread across the 16 lrow lanes
        const bool m4ok = (lrow < 13);
#pragma unroll
        for (int r = 0; r < 4; ++r) {
            float v[5];
#pragma unroll
            for (int ct = 0; ct < 5; ++ct) v[ct] = s[ct][r];
            float mx = fmaxf(fmaxf(fmaxf(v[0], v[1]), fmaxf(v[2], v[3])),
                             m4ok ? v[4] : -1e30f);
#pragma unroll
            for (int off = 1; off < 16; off <<= 1)
                mx = fmaxf(mx, __shfl_xor(mx, off));
            float e[5];
            float sum = 0.f;
#pragma unroll
            for (int ct = 0; ct < 4; ++ct) { e[ct] = __expf(v[ct] - mx); sum += e[ct]; }
            e[4] = m4ok ? __expf(v[4] - mx) : 0.f;
            sum += e[4];
#pragma unroll
            for (int off = 1; off < 16; off <<= 1)
                sum += __shfl_xor(sum, off);
            float rinv = 1.0f / sum;
            int prow = lk * 4 + r;
#pragma unroll
            for (int ct = 0; ct < 5; ++ct)
                Pl[w][prow][ct * 16 + lrow] = f2h(e[ct] * rinv);
        }

        // PV: O[16 x 64] += P[16 x 96] @ V^T-stored
        const _Float16* Vb = Vt + (size_t)(b * NH + h) * 64 * M_PAD;
        f32x4 o[4];
#pragma unroll
        for (int i = 0; i < 4; ++i)
#pragma unroll
            for (int e2 = 0; e2 < 4; ++e2) o[i][e2] = 0.f;
#pragma unroll
        for (int kk = 0; kk < 3; ++kk) {
            f16x8 pa = *(const f16x8*)&Pl[w][lrow][kk * 32 + lk * 8];
#pragma unroll
            for (int ctd = 0; ctd < 4; ++ctd) {
                f16x8 vf = *(const f16x8*)(Vb + (size_t)(ctd * 16 + lrow) * M_PAD + kk * 32 + lk * 8);
                o[ctd] = __builtin_amdgcn_mfma_f32_16x16x32_f16(pa, vf, o[ctd], 0, 0, 0);
            }
        }

#pragma unroll
        for (int ctd = 0; ctd < 4; ++ctd)
#pragma unroll
            for (int r = 0; r < 4; ++r) {
                size_t row = rowbase + lk * 4 + r;
                int col = h * 64 + ctd * 16 + lrow;
                AO[row * 512 + col] = f2h(o[ctd][r]);
            }
    }
}

// ---------------------------------------------------------------------------
extern "C" void kernel_launch(void* const* d_in, const int* in_sizes, int n_in,
                              void* d_out, int out_size, void* d_ws, size_t ws_size,
                              hipStream_t stream)
{
    (void)in_sizes; (void)n_in; (void)out_size; (void)ws_size;
    const float* x    = (const float*)d_in[0];
    const float* cond = (const float*)d_in[1];
    const float* Wq   = (const float*)d_in[2];
    const float* Wk   = (const float*)d_in[3];
    const float* Wv   = (const float*)d_in[4];
    const float* Wo   = (const float*)d_in[5];
    const float* bo   = (const float*)d_in[6];

    char* ws = (char*)d_ws;
    _Float16* WqT = (_Float16*)(ws);               // 512*512*2 = 524288
    _Float16* WoT = (_Float16*)(ws + 524288);      // 524288
    _Float16* WkT = (_Float16*)(ws + 1048576);     // 512*768*2 = 786432
    _Float16* WvT = (_Float16*)(ws + 1835008);     // 786432
    _Float16* Kp  = (_Float16*)(ws + 2621440);     // 16*8*96*64*2 = 1572864
    _Float16* Vt  = (_Float16*)(ws + 4194304);     // 1572864
    _Float16* Q   = (_Float16*)(ws + 5767168);     // 16*4096*512*2 = 67108864
    // total: 72,876,032 bytes (~69.5 MB); AO aliases Q (read-before-write per wave)

    prep<<<dim3(16, 24, 4), 256, 0, stream>>>(Wq, Wk, Wv, Wo, WqT, WkT, WvT, WoT);
    kv_proj<<<dim3(8, 16, 2), 256, 0, stream>>>(cond, WkT, WvT, Kp, Vt);
    gemm512<0><<<dim3(2048), 256, 0, stream>>>(x, WqT, Q, nullptr, 0.125f);
    attn<<<dim3(64, 16), 256, 0, stream>>>(Q, Kp, Vt, Q /*AO aliases Q*/);
    gemm512<1><<<dim3(2048), 256, 0, stream>>>(Q, WoT, d_out, bo, 1.0f);
}

// Round 2
// 265.940 us; speedup vs baseline: 1.0967x; 1.0967x over previous
//
#include <hip/hip_runtime.h>

typedef __attribute__((ext_vector_type(8))) _Float16 f16x8;
typedef __attribute__((ext_vector_type(4))) float f32x4;

#define B_SZ   16
#define N_SEQ  4096
#define M_CTX  77
#define M_PAD  96
#define NH     8

__device__ __forceinline__ _Float16 f2h(float x) { return (_Float16)x; }

// async global->LDS, 16B per lane. dst must be wave-uniform base; HW writes
// dst + lane*16. Source address is per-lane (pre-swizzled by caller).
__device__ __forceinline__ void gload16(const void* g, void* l) {
    __builtin_amdgcn_global_load_lds(
        (const __attribute__((address_space(1))) unsigned int*)g,
        (__attribute__((address_space(3))) unsigned int*)l, 16, 0, 0);
}

// ---------------------------------------------------------------------------
// convert: x fp32 -> x_h f16 (memory-bound, 201 MB traffic)
// ---------------------------------------------------------------------------
__global__ __launch_bounds__(256)
void convert(const float4* __restrict__ x, f16x8* __restrict__ xh, int n8)
{
    int idx = blockIdx.x * 256 + threadIdx.x;
    int stride = gridDim.x * 256;
    for (int i = idx; i < n8; i += stride) {
        float4 a = x[2 * i];
        float4 b = x[2 * i + 1];
        f16x8 o;
        o[0] = f2h(a.x); o[1] = f2h(a.y); o[2] = f2h(a.z); o[3] = f2h(a.w);
        o[4] = f2h(b.x); o[5] = f2h(b.y); o[6] = f2h(b.z); o[7] = f2h(b.w);
        xh[i] = o;
    }
}

// ---------------------------------------------------------------------------
// prep: W [K][512] fp32 -> WT [512][K] f16 (LDS-tiled transpose).
// Wq gets the 1/sqrt(D_HEAD)=0.125 softmax scale folded in.
// grid (16, 24, 4): z selects matrix; block 256
// ---------------------------------------------------------------------------
__global__ __launch_bounds__(256)
void prep(const float* __restrict__ Wq, const float* __restrict__ Wk,
          const float* __restrict__ Wv, const float* __restrict__ Wo,
          _Float16* __restrict__ WqT, _Float16* __restrict__ WkT,
          _Float16* __restrict__ WvT, _Float16* __restrict__ WoT)
{
    __shared__ float t[32][33];
    const float* W; _Float16* WT; int K; float scale = 1.0f;
    switch (blockIdx.z) {
        case 0:  W = Wq; WT = WqT; K = 512; scale = 0.125f; break;
        case 1:  W = Wk; WT = WkT; K = 768; break;
        case 2:  W = Wv; WT = WvT; K = 768; break;
        default: W = Wo; WT = WoT; K = 512; break;
    }
    const int ky = blockIdx.y;
    if (ky * 32 >= K) return;
    const int nx = blockIdx.x;
    const int tr = threadIdx.x >> 5, tc = threadIdx.x & 31;
#pragma unroll
    for (int i = 0; i < 4; ++i) {
        int kr = tr + i * 8;
        t[kr][tc] = W[(size_t)(ky * 32 + kr) * 512 + nx * 32 + tc];
    }
    __syncthreads();
#pragma unroll
    for (int i = 0; i < 4; ++i) {
        int nr = tr + i * 8;
        WT[(size_t)(nx * 32 + nr) * K + ky * 32 + tc] = f2h(t[tc][nr] * scale);
    }
}

// ---------------------------------------------------------------------------
// kv_proj: K[b,h,m,d] (m padded to 96 w/ zeros) and V transposed [b,h,d,m]
// grid (8 h, 16 b, 2 kv); block 256 = 4 waves
// ---------------------------------------------------------------------------
__global__ __launch_bounds__(256)
void kv_proj(const float* __restrict__ cond, const _Float16* __restrict__ WkT,
             const _Float16* __restrict__ WvT, _Float16* __restrict__ Kp,
             _Float16* __restrict__ Vt)
{
    const int tid = threadIdx.x;
    const int l = tid & 63, w = tid >> 6;
    const int lrow = l & 15, lk = l >> 4;
    const int h = blockIdx.x, b = blockIdx.y, which = blockIdx.z;
    const _Float16* WT = which ? WvT : WkT;
    const float* cb = cond + (size_t)b * M_CTX * 768;

    f32x4 acc[5];
#pragma unroll
    for (int i = 0; i < 5; ++i)
#pragma unroll
        for (int e = 0; e < 4; ++e) acc[i][e] = 0.f;

    const int n = h * 64 + w * 16 + lrow;
    for (int kk = 0; kk < 24; ++kk) {
        f16x8 bfrag = *(const f16x8*)(WT + (size_t)n * 768 + kk * 32 + lk * 8);
#pragma unroll
        for (int rt = 0; rt < 5; ++rt) {
            int m = rt * 16 + lrow;
            f16x8 afrag;
#pragma unroll
            for (int j = 0; j < 8; ++j) afrag[j] = (_Float16)0.f;
            if (m < M_CTX) {
                const float* a = cb + (size_t)m * 768 + kk * 32 + lk * 8;
                float4 f0 = *(const float4*)a;
                float4 f1 = *(const float4*)(a + 4);
                afrag[0] = f2h(f0.x); afrag[1] = f2h(f0.y);
                afrag[2] = f2h(f0.z); afrag[3] = f2h(f0.w);
                afrag[4] = f2h(f1.x); afrag[5] = f2h(f1.y);
                afrag[6] = f2h(f1.z); afrag[7] = f2h(f1.w);
            }
            acc[rt] = __builtin_amdgcn_mfma_f32_16x16x32_f16(afrag, bfrag, acc[rt], 0, 0, 0);
        }
    }

    const int bh = b * NH + h;
    const int d = w * 16 + lrow;
    if (which == 0) {
#pragma unroll
        for (int rt = 0; rt < 5; ++rt)
#pragma unroll
            for (int r = 0; r < 4; ++r) {
                int m = rt * 16 + lk * 4 + r;
                Kp[((size_t)bh * M_PAD + m) * 64 + d] = f2h(acc[rt][r]);
            }
#pragma unroll
        for (int r = 0; r < 4; ++r) {
            int m = 80 + lk * 4 + r;
            Kp[((size_t)bh * M_PAD + m) * 64 + d] = (_Float16)0.f;
        }
    } else {
#pragma unroll
        for (int rt = 0; rt < 5; ++rt)
#pragma unroll
            for (int r = 0; r < 4; ++r) {
                int m = rt * 16 + lk * 4 + r;
                Vt[((size_t)bh * 64 + d) * M_PAD + m] = f2h(acc[rt][r]);
            }
#pragma unroll
        for (int r = 0; r < 4; ++r) {
            int m = 80 + lk * 4 + r;
            Vt[((size_t)bh * 64 + d) * M_PAD + m] = (_Float16)0.f;
        }
    }
}

// ---------------------------------------------------------------------------
// gemm512: C[65536][512] = A[65536][512] @ B, BT[512][512] f16 given.
// m97 structure: 128x128 tile, BK=64, global_load_lds w/ pre-swizzled source,
// XOR slot swizzle on ds_read side (LDS linear). XCD-chunked block swizzle.
// EMODE 0: C f16; EMODE 1: C fp32 + bias.
// ---------------------------------------------------------------------------
template<int EMODE>
__global__ __launch_bounds__(256)
void gemm512(const _Float16* __restrict__ A, const _Float16* __restrict__ BT,
             void* __restrict__ Cv, const float* __restrict__ bias)
{
    __shared__ _Float16 As[128 * 64];
    __shared__ _Float16 Bs[128 * 64];

    // XCD-chunked swizzle: nwg=2048 (divisible by 8)
    const int bid = blockIdx.x;
    const int wg = (bid & 7) * 256 + (bid >> 3);
    const int rb = wg >> 2;        // 0..511
    const int cb = wg & 3;         // 0..3
    const size_t row0 = (size_t)rb * 128;
    const int col0 = cb * 128;

    const int tid = threadIdx.x;
    const int l = tid & 63;
    const int w = tid >> 6;
    const int wy = w >> 1, wx = w & 1;
    const int lrow = l & 15, lk = l >> 4;

    f32x4 acc[4][4];
#pragma unroll
    for (int i = 0; i < 4; ++i)
#pragma unroll
        for (int j = 0; j < 4; ++j)
#pragma unroll
            for (int e = 0; e < 4; ++e) acc[i][j][e] = 0.f;

    // staging source: lane l covers row (seg*8 + (l>>3)), 16B col-slot
    // (l&7) ^ ((l>>3)&7)  [inverse swizzle so LDS linear write lands the
    // involution the ds_read side expects]
    const int srow_in_seg = l >> 3;                    // 0..7
    const int sslot = (l & 7) ^ (srow_in_seg & 7);     // pre-swizzled col slot
    const _Float16* a_src0 = A + (row0 + (size_t)(w * 32 + srow_in_seg)) * 512 + sslot * 8;
    const _Float16* b_src0 = BT + ((size_t)(col0 + w * 32 + srow_in_seg)) * 512 + sslot * 8;

    for (int kt = 0; kt < 8; ++kt) {
        const _Float16* ak = a_src0 + kt * 64;
        const _Float16* bk = b_src0 + kt * 64;
#pragma unroll
        for (int s = 0; s < 4; ++s) {
            gload16(ak + (size_t)s * 8 * 512, As + (w * 4 + s) * 512);
            gload16(bk + (size_t)s * 8 * 512, Bs + (w * 4 + s) * 512);
        }
        __syncthreads();   // drains vmcnt: tiles ready

#pragma unroll
        for (int kk = 0; kk < 2; ++kk) {
            f16x8 af[4], bf[4];
#pragma unroll
            for (int mt = 0; mt < 4; ++mt) {
                int R = wy * 64 + mt * 16 + lrow;
                int p = (kk * 4 + lk) ^ (lrow & 7);
                af[mt] = *(const f16x8*)&As[R * 64 + p * 8];
            }
#pragma unroll
            for (int nt = 0; nt < 4; ++nt) {
                int R = wx * 64 + nt * 16 + lrow;
                int p = (kk * 4 + lk) ^ (lrow & 7);
                bf[nt] = *(const f16x8*)&Bs[R * 64 + p * 8];
            }
#pragma unroll
            for (int mt = 0; mt < 4; ++mt)
#pragma unroll
                for (int nt = 0; nt < 4; ++nt)
                    acc[mt][nt] = __builtin_amdgcn_mfma_f32_16x16x32_f16(af[mt], bf[nt], acc[mt][nt], 0, 0, 0);
        }
        __syncthreads();   // protect LDS before next stage overwrites
    }

    // epilogue
#pragma unroll
    for (int mt = 0; mt < 4; ++mt)
#pragma unroll
        for (int nt = 0; nt < 4; ++nt)
#pragma unroll
            for (int r = 0; r < 4; ++r) {
                size_t row = row0 + wy * 64 + mt * 16 + lk * 4 + r;
                int col = col0 + wx * 64 + nt * 16 + lrow;
                float v = acc[mt][nt][r];
                if (EMODE == 0) {
                    ((_Float16*)Cv)[row * 512 + col] = f2h(v);
                } else {
                    ((float*)Cv)[row * 512 + col] = v + bias[col];
                }
            }
}

// ---------------------------------------------------------------------------
// attn: per (b, 64-row tile): per head: S=QK^T (scale pre-folded into Wq),
// softmax (cols 77..95 masked/zero), P@V.
// grid (64 tiles, 16 b); block 256 = 4 waves, wave = 16 Q rows.
// ---------------------------------------------------------------------------
__global__ __launch_bounds__(256)
void attn(const _Float16* __restrict__ Q, const _Float16* __restrict__ Kp,
          const _Float16* __restrict__ Vt, _Float16* __restrict__ AO)
{
    __shared__ _Float16 Pl[4][16][104];   // stride 104 -> 16B aligned, 2-way banks
    const int tid = threadIdx.x;
    const int l = tid & 63, w = tid >> 6;
    const int lrow = l & 15, lk = l >> 4;
    const int b = blockIdx.y, tile = blockIdx.x;
    const size_t rowbase = (size_t)b * N_SEQ + tile * 64 + w * 16;

    // zero pad columns 80..95 once (77..79 masked each head)
    for (int idx = l; idx < 256; idx += 64)
        Pl[w][idx >> 4][80 + (idx & 15)] = (_Float16)0.f;

    for (int h = 0; h < NH; ++h) {
        const size_t qoff = (rowbase + lrow) * 512 + h * 64;
        f16x8 qf0 = *(const f16x8*)(Q + qoff + lk * 8);
        f16x8 qf1 = *(const f16x8*)(Q + qoff + 32 + lk * 8);

        const _Float16* Kb = Kp + (size_t)(b * NH + h) * M_PAD * 64;
        f32x4 s[5];
#pragma unroll
        for (int i = 0; i < 5; ++i)
#pragma unroll
            for (int e = 0; e < 4; ++e) s[i][e] = 0.f;

#pragma unroll
        for (int ct = 0; ct < 5; ++ct) {
            f16x8 kf0 = *(const f16x8*)(Kb + (size_t)(ct * 16 + lrow) * 64 + lk * 8);
            f16x8 kf1 = *(const f16x8*)(Kb + (size_t)(ct * 16 + lrow) * 64 + 32 + lk * 8);
            s[ct] = __builtin_amdgcn_mfma_f32_16x16x32_f16(qf0, kf0, s[ct], 0, 0, 0);
            s[ct] = __builtin_amdgcn_mfma_f32_16x16x32_f16(qf1, kf1, s[ct], 0, 0, 0);
        }

        const bool m4ok = (lrow < 13);
#pragma unroll
        for (int r = 0; r < 4; ++r) {
            float v[5];
#pragma unroll
            for (int ct = 0; ct < 5; ++ct) v[ct] = s[ct][r];
            float mx = fmaxf(fmaxf(fmaxf(v[0], v[1]), fmaxf(v[2], v[3])),
                             m4ok ? v[4] : -1e30f);
#pragma unroll
            for (int off = 1; off < 16; off <<= 1)
                mx = fmaxf(mx, __shfl_xor(mx, off));
            float e[5];
            float sum = 0.f;
#pragma unroll
            for (int ct = 0; ct < 4; ++ct) { e[ct] = __expf(v[ct] - mx); sum += e[ct]; }
            e[4] = m4ok ? __expf(v[4] - mx) : 0.f;
            sum += e[4];
#pragma unroll
            for (int off = 1; off < 16; off <<= 1)
                sum += __shfl_xor(sum, off);
            float rinv = 1.0f / sum;
            int prow = lk * 4 + r;
#pragma unroll
            for (int ct = 0; ct < 5; ++ct)
                Pl[w][prow][ct * 16 + lrow] = f2h(e[ct] * rinv);
        }

        const _Float16* Vb = Vt + (size_t)(b * NH + h) * 64 * M_PAD;
        f32x4 o[4];
#pragma unroll
        for (int i = 0; i < 4; ++i)
#pragma unroll
            for (int e2 = 0; e2 < 4; ++e2) o[i][e2] = 0.f;
#pragma unroll
        for (int kk = 0; kk < 3; ++kk) {
            f16x8 pa = *(const f16x8*)&Pl[w][lrow][kk * 32 + lk * 8];
#pragma unroll
            for (int ctd = 0; ctd < 4; ++ctd) {
                f16x8 vf = *(const f16x8*)(Vb + (size_t)(ctd * 16 + lrow) * M_PAD + kk * 32 + lk * 8);
                o[ctd] = __builtin_amdgcn_mfma_f32_16x16x32_f16(pa, vf, o[ctd], 0, 0, 0);
            }
        }

#pragma unroll
        for (int ctd = 0; ctd < 4; ++ctd)
#pragma unroll
            for (int r = 0; r < 4; ++r) {
                size_t row = rowbase + lk * 4 + r;
                int col = h * 64 + ctd * 16 + lrow;
                AO[row * 512 + col] = f2h(o[ctd][r]);
            }
    }
}

// ---------------------------------------------------------------------------
extern "C" void kernel_launch(void* const* d_in, const int* in_sizes, int n_in,
                              void* d_out, int out_size, void* d_ws, size_t ws_size,
                              hipStream_t stream)
{
    (void)in_sizes; (void)n_in; (void)out_size; (void)ws_size;
    const float* x    = (const float*)d_in[0];
    const float* cond = (const float*)d_in[1];
    const float* Wq   = (const float*)d_in[2];
    const float* Wk   = (const float*)d_in[3];
    const float* Wv   = (const float*)d_in[4];
    const float* Wo   = (const float*)d_in[5];
    const float* bo   = (const float*)d_in[6];

    char* ws = (char*)d_ws;
    _Float16* WqT = (_Float16*)(ws);               // 512*512*2 = 524288
    _Float16* WoT = (_Float16*)(ws + 524288);      // 524288
    _Float16* WkT = (_Float16*)(ws + 1048576);     // 512*768*2 = 786432
    _Float16* WvT = (_Float16*)(ws + 1835008);     // 786432
    _Float16* Kp  = (_Float16*)(ws + 2621440);     // 16*8*96*64*2 = 1572864
    _Float16* Vt  = (_Float16*)(ws + 4194304);     // 1572864
    _Float16* xh  = (_Float16*)(ws + 5767168);     // 16*4096*512*2 = 67108864
    _Float16* AO  = xh;                            // aliases xh (dead after Q-GEMM)
    // total ws: 72,876,032 bytes (~69.5 MB) -- same as round 1
    _Float16* Q   = (_Float16*)d_out;              // Q f16 scratch in d_out
                                                   // (dead before O-GEMM writes)

    prep<<<dim3(16, 24, 4), 256, 0, stream>>>(Wq, Wk, Wv, Wo, WqT, WkT, WvT, WoT);
    kv_proj<<<dim3(8, 16, 2), 256, 0, stream>>>(cond, WkT, WvT, Kp, Vt);
    convert<<<dim3(2048), 256, 0, stream>>>((const float4*)x, (f16x8*)xh, 16 * 4096 * 512 / 8);
    gemm512<0><<<dim3(2048), 256, 0, stream>>>(xh, WqT, Q, nullptr);
    attn<<<dim3(64, 16), 256, 0, stream>>>(Q, Kp, Vt, AO);
    gemm512<1><<<dim3(2048), 256, 0, stream>>>(AO, WoT, d_out, bo);
}

// Round 3
// 228.070 us; speedup vs baseline: 1.2788x; 1.1660x over previous
//
#include <hip/hip_runtime.h>

typedef __attribute__((ext_vector_type(8))) _Float16 f16x8;
typedef __attribute__((ext_vector_type(4))) float f32x4;

#define B_SZ   16
#define N_SEQ  4096
#define M_CTX  77
#define M_PAD  96
#define NH     8

__device__ __forceinline__ _Float16 f2h(float x) { return (_Float16)x; }

// async global->LDS, 16B per lane. dst = wave-uniform base; HW writes
// dst + lane*16. Source address is per-lane.
__device__ __forceinline__ void gload16(const void* g, void* l) {
    __builtin_amdgcn_global_load_lds(
        (const __attribute__((address_space(1))) unsigned int*)g,
        (__attribute__((address_space(3))) unsigned int*)l, 16, 0, 0);
}

// ---- DPP 16-lane butterfly reductions (XOR masks {1,2,7,15} span 0..15) ----
template<int C>
__device__ __forceinline__ float dppf(float x) {
    union { float f; int i; } u, v;
    u.f = x;
    v.i = __builtin_amdgcn_mov_dpp(u.i, C, 0xF, 0xF, true);
    return v.f;
}
__device__ __forceinline__ float rmax16(float x) {
    x = fmaxf(x, dppf<0xB1>(x));    // quad_perm(1,0,3,2)  xor 1
    x = fmaxf(x, dppf<0x4E>(x));    // quad_perm(2,3,0,1)  xor 2
    x = fmaxf(x, dppf<0x141>(x));   // row_half_mirror     xor 7
    x = fmaxf(x, dppf<0x140>(x));   // row_mirror          xor 15
    return x;
}
__device__ __forceinline__ float rsum16(float x) {
    x += dppf<0xB1>(x);
    x += dppf<0x4E>(x);
    x += dppf<0x141>(x);
    x += dppf<0x140>(x);
    return x;
}

// ---------------------------------------------------------------------------
// convert: x fp32 -> x_h f16 (memory-bound, 201 MB traffic)
// ---------------------------------------------------------------------------
__global__ __launch_bounds__(256)
void convert(const float4* __restrict__ x, f16x8* __restrict__ xh, int n8)
{
    int idx = blockIdx.x * 256 + threadIdx.x;
    int stride = gridDim.x * 256;
    for (int i = idx; i < n8; i += stride) {
        float4 a = x[2 * i];
        float4 b = x[2 * i + 1];
        f16x8 o;
        o[0] = f2h(a.x); o[1] = f2h(a.y); o[2] = f2h(a.z); o[3] = f2h(a.w);
        o[4] = f2h(b.x); o[5] = f2h(b.y); o[6] = f2h(b.z); o[7] = f2h(b.w);
        xh[i] = o;
    }
}

// ---------------------------------------------------------------------------
// prep: W [K][512] fp32 -> WT [512][K] f16 (LDS-tiled transpose).
// Wq gets the 1/sqrt(D_HEAD)=0.125 softmax scale folded in.
// ---------------------------------------------------------------------------
__global__ __launch_bounds__(256)
void prep(const float* __restrict__ Wq, const float* __restrict__ Wk,
          const float* __restrict__ Wv, const float* __restrict__ Wo,
          _Float16* __restrict__ WqT, _Float16* __restrict__ WkT,
          _Float16* __restrict__ WvT, _Float16* __restrict__ WoT)
{
    __shared__ float t[32][33];
    const float* W; _Float16* WT; int K; float scale = 1.0f;
    switch (blockIdx.z) {
        case 0:  W = Wq; WT = WqT; K = 512; scale = 0.125f; break;
        case 1:  W = Wk; WT = WkT; K = 768; break;
        case 2:  W = Wv; WT = WvT; K = 768; break;
        default: W = Wo; WT = WoT; K = 512; break;
    }
    const int ky = blockIdx.y;
    if (ky * 32 >= K) return;
    const int nx = blockIdx.x;
    const int tr = threadIdx.x >> 5, tc = threadIdx.x & 31;
#pragma unroll
    for (int i = 0; i < 4; ++i) {
        int kr = tr + i * 8;
        t[kr][tc] = W[(size_t)(ky * 32 + kr) * 512 + nx * 32 + tc];
    }
    __syncthreads();
#pragma unroll
    for (int i = 0; i < 4; ++i) {
        int nr = tr + i * 8;
        WT[(size_t)(nx * 32 + nr) * K + ky * 32 + tc] = f2h(t[tc][nr] * scale);
    }
}

// ---------------------------------------------------------------------------
// kv_proj: writes K and V in BANK-SWIZZLED global layouts so attn can stage
// them to LDS linearly with global_load_lds and read conflict-free:
//   Kswz[bh][m][ ((d>>3)^(m&7))*8 + (d&7) ]   m in 0..95 (zeros >= 77)
//   Vswz[bh][d][ ((m>>3)^(d&7))*8 + (m&7) ]   rows of 128 f16 (slots 0..11 used)
// grid (8 h, 16 b, 2 kv); block 256 = 4 waves
// ---------------------------------------------------------------------------
__global__ __launch_bounds__(256)
void kv_proj(const float* __restrict__ cond, const _Float16* __restrict__ WkT,
             const _Float16* __restrict__ WvT, _Float16* __restrict__ Kswz,
             _Float16* __restrict__ Vswz)
{
    const int tid = threadIdx.x;
    const int l = tid & 63, w = tid >> 6;
    const int lrow = l & 15, lk = l >> 4;
    const int h = blockIdx.x, b = blockIdx.y, which = blockIdx.z;
    const _Float16* WT = which ? WvT : WkT;
    const float* cb = cond + (size_t)b * M_CTX * 768;

    f32x4 acc[5];
#pragma unroll
    for (int i = 0; i < 5; ++i)
#pragma unroll
        for (int e = 0; e < 4; ++e) acc[i][e] = 0.f;

    const int n = h * 64 + w * 16 + lrow;
    for (int kk = 0; kk < 24; ++kk) {
        f16x8 bfrag = *(const f16x8*)(WT + (size_t)n * 768 + kk * 32 + lk * 8);
#pragma unroll
        for (int rt = 0; rt < 5; ++rt) {
            int m = rt * 16 + lrow;
            f16x8 afrag;
#pragma unroll
            for (int j = 0; j < 8; ++j) afrag[j] = (_Float16)0.f;
            if (m < M_CTX) {
                const float* a = cb + (size_t)m * 768 + kk * 32 + lk * 8;
                float4 f0 = *(const float4*)a;
                float4 f1 = *(const float4*)(a + 4);
                afrag[0] = f2h(f0.x); afrag[1] = f2h(f0.y);
                afrag[2] = f2h(f0.z); afrag[3] = f2h(f0.w);
                afrag[4] = f2h(f1.x); afrag[5] = f2h(f1.y);
                afrag[6] = f2h(f1.z); afrag[7] = f2h(f1.w);
            }
            acc[rt] = __builtin_amdgcn_mfma_f32_16x16x32_f16(afrag, bfrag, acc[rt], 0, 0, 0);
        }
    }

    const int bh = b * NH + h;
    const int d = w * 16 + lrow;       // output feature within head
    const int dhi = d >> 3, dlo = d & 7;
    if (which == 0) {
        _Float16* Kb = Kswz + (size_t)bh * (M_PAD * 64);
#pragma unroll
        for (int rt = 0; rt < 5; ++rt)
#pragma unroll
            for (int r = 0; r < 4; ++r) {
                int m = rt * 16 + lk * 4 + r;
                Kb[m * 64 + ((dhi ^ (m & 7)) * 8) + dlo] = f2h(acc[rt][r]);
            }
#pragma unroll
        for (int r = 0; r < 4; ++r) {
            int m = 80 + lk * 4 + r;
            Kb[m * 64 + ((dhi ^ (m & 7)) * 8) + dlo] = (_Float16)0.f;
        }
    } else {
        _Float16* Vb = Vswz + (size_t)bh * (64 * 128);
#pragma unroll
        for (int rt = 0; rt < 5; ++rt)
#pragma unroll
            for (int r = 0; r < 4; ++r) {
                int m = rt * 16 + lk * 4 + r;
                Vb[d * 128 + (((m >> 3) ^ dlo) * 8) + (m & 7)] = f2h(acc[rt][r]);
            }
#pragma unroll
        for (int r = 0; r < 4; ++r) {
            int m = 80 + lk * 4 + r;
            Vb[d * 128 + (((m >> 3) ^ dlo) * 8) + (m & 7)] = (_Float16)0.f;
        }
    }
}

// ---------------------------------------------------------------------------
// gemm512: C[65536][512] = A[65536][512] @ B, BT[512][512] f16 given.
// m97 structure: 128x128 tile, BK=64, global_load_lds w/ pre-swizzled source.
// EMODE 0: C f16; EMODE 1: C fp32 + bias.
// ---------------------------------------------------------------------------
template<int EMODE>
__global__ __launch_bounds__(256)
void gemm512(const _Float16* __restrict__ A, const _Float16* __restrict__ BT,
             void* __restrict__ Cv, const float* __restrict__ bias)
{
    __shared__ _Float16 As[128 * 64];
    __shared__ _Float16 Bs[128 * 64];

    const int bid = blockIdx.x;
    const int wg = (bid & 7) * 256 + (bid >> 3);
    const int rb = wg >> 2;
    const int cb = wg & 3;
    const size_t row0 = (size_t)rb * 128;
    const int col0 = cb * 128;

    const int tid = threadIdx.x;
    const int l = tid & 63;
    const int w = tid >> 6;
    const int wy = w >> 1, wx = w & 1;
    const int lrow = l & 15, lk = l >> 4;

    f32x4 acc[4][4];
#pragma unroll
    for (int i = 0; i < 4; ++i)
#pragma unroll
        for (int j = 0; j < 4; ++j)
#pragma unroll
            for (int e = 0; e < 4; ++e) acc[i][j][e] = 0.f;

    const int srow_in_seg = l >> 3;
    const int sslot = (l & 7) ^ (srow_in_seg & 7);
    const _Float16* a_src0 = A + (row0 + (size_t)(w * 32 + srow_in_seg)) * 512 + sslot * 8;
    const _Float16* b_src0 = BT + ((size_t)(col0 + w * 32 + srow_in_seg)) * 512 + sslot * 8;

    for (int kt = 0; kt < 8; ++kt) {
        const _Float16* ak = a_src0 + kt * 64;
        const _Float16* bk = b_src0 + kt * 64;
#pragma unroll
        for (int s = 0; s < 4; ++s) {
            gload16(ak + (size_t)s * 8 * 512, As + (w * 4 + s) * 512);
            gload16(bk + (size_t)s * 8 * 512, Bs + (w * 4 + s) * 512);
        }
        __syncthreads();

#pragma unroll
        for (int kk = 0; kk < 2; ++kk) {
            f16x8 af[4], bf[4];
#pragma unroll
            for (int mt = 0; mt < 4; ++mt) {
                int R = wy * 64 + mt * 16 + lrow;
                int p = (kk * 4 + lk) ^ (lrow & 7);
                af[mt] = *(const f16x8*)&As[R * 64 + p * 8];
            }
#pragma unroll
            for (int nt = 0; nt < 4; ++nt) {
                int R = wx * 64 + nt * 16 + lrow;
                int p = (kk * 4 + lk) ^ (lrow & 7);
                bf[nt] = *(const f16x8*)&Bs[R * 64 + p * 8];
            }
#pragma unroll
            for (int mt = 0; mt < 4; ++mt)
#pragma unroll
                for (int nt = 0; nt < 4; ++nt)
                    acc[mt][nt] = __builtin_amdgcn_mfma_f32_16x16x32_f16(af[mt], bf[nt], acc[mt][nt], 0, 0, 0);
        }
        __syncthreads();
    }

#pragma unroll
    for (int mt = 0; mt < 4; ++mt)
#pragma unroll
        for (int nt = 0; nt < 4; ++nt)
#pragma unroll
            for (int r = 0; r < 4; ++r) {
                size_t row = row0 + wy * 64 + mt * 16 + lk * 4 + r;
                int col = col0 + wx * 64 + nt * 16 + lrow;
                float v = acc[mt][nt][r];
                if (EMODE == 0) {
                    ((_Float16*)Cv)[row * 512 + col] = f2h(v);
                } else {
                    ((float*)Cv)[row * 512 + col] = v + bias[col];
                }
            }
}

// ---------------------------------------------------------------------------
// attn: one block = one (b,h) x 256 Q-rows. K,V staged to LDS once (swizzled
// layouts pre-baked in global). 4 waves x 64 rows. DPP softmax reductions,
// deferred 1/sum normalization into the O epilogue.
// grid (16 chunks, 8 h, 16 b); block 256.
// ---------------------------------------------------------------------------
__global__ __launch_bounds__(256)
void attn(const _Float16* __restrict__ Q, const _Float16* __restrict__ Kswz,
          const _Float16* __restrict__ Vswz, _Float16* __restrict__ AO)
{
    __shared__ _Float16 Ks[M_PAD * 64];    // 12KB: row m, slot s at s^(m&7)
    __shared__ _Float16 Vs[64 * 128];      // 16KB: row d, slot s at s^(d&7)
    __shared__ _Float16 Pl[4][16][104];    // 13KB: per-wave P tile

    const int tid = threadIdx.x;
    const int l = tid & 63, w = tid >> 6;
    const int lrow = l & 15, lk = l >> 4;
    const int chunk = blockIdx.x, h = blockIdx.y, b = blockIdx.z;
    const int bh = b * NH + h;

    // ---- stage K (12x1KB) and V (16x1KB) ----
    {
        const _Float16* Kg = Kswz + (size_t)bh * (M_PAD * 64);
        const _Float16* Vg = Vswz + (size_t)bh * (64 * 128);
#pragma unroll
        for (int i = 0; i < 3; ++i) {
            int c = w * 3 + i;
            gload16(Kg + c * 512 + l * 8, Ks + c * 512);
        }
#pragma unroll
        for (int i = 0; i < 4; ++i) {
            int c = w * 4 + i;
            gload16(Vg + c * 512 + l * 8, Vs + c * 512);
        }
    }

    // ---- Q fragments: 64 rows per wave, this block's head slice ----
    const size_t row0 = (size_t)b * N_SEQ + chunk * 256 + w * 64;
    f16x8 af[4][2];
    {
        const _Float16* Qb = Q + (row0 + lrow) * 512 + h * 64 + lk * 8;
#pragma unroll
        for (int mt = 0; mt < 4; ++mt)
#pragma unroll
            for (int kk = 0; kk < 2; ++kk)
                af[mt][kk] = *(const f16x8*)(Qb + (size_t)mt * 16 * 512 + kk * 32);
    }

    // zero P pad cols 80..95 (cols 96..103 never read)
    for (int idx = l; idx < 256; idx += 64)
        Pl[w][idx >> 4][80 + (idx & 15)] = (_Float16)0.f;

    __syncthreads();   // drains vmcnt: K/V in LDS, Q frags in regs

    const bool m4ok = (lrow < 13);     // tile-4 col = 64+lrow valid iff < 77
    const int kswz = lrow & 7;

#pragma unroll
    for (int mt = 0; mt < 4; ++mt) {
        // ---- S = Q K^T (cols 0..79) ----
        f32x4 s[5];
#pragma unroll
        for (int i = 0; i < 5; ++i)
#pragma unroll
            for (int e = 0; e < 4; ++e) s[i][e] = 0.f;
#pragma unroll
        for (int kk = 0; kk < 2; ++kk)
#pragma unroll
            for (int ct = 0; ct < 5; ++ct) {
                f16x8 kf = *(const f16x8*)&Ks[(ct * 16 + lrow) * 64 + (((kk * 4 + lk) ^ kswz) * 8)];
                s[ct] = __builtin_amdgcn_mfma_f32_16x16x32_f16(af[mt][kk], kf, s[ct], 0, 0, 0);
            }

        // ---- softmax: DPP butterfly over the 16 lrow lanes ----
        float rinv[4];
#pragma unroll
        for (int r = 0; r < 4; ++r) {
            float v0 = s[0][r], v1 = s[1][r], v2 = s[2][r], v3 = s[3][r], v4 = s[4][r];
            float mx = fmaxf(fmaxf(v0, v1), fmaxf(v2, v3));
            mx = fmaxf(mx, m4ok ? v4 : -1e30f);
            mx = rmax16(mx);
            float e0 = __expf(v0 - mx), e1 = __expf(v1 - mx);
            float e2 = __expf(v2 - mx), e3 = __expf(v3 - mx);
            float e4 = m4ok ? __expf(v4 - mx) : 0.f;
            float sum = ((e0 + e1) + (e2 + e3)) + e4;
            sum = rsum16(sum);
            rinv[r] = 1.0f / sum;      // uniform across lrow after reduce
            int prow = lk * 4 + r;
            Pl[w][prow][lrow]      = f2h(e0);
            Pl[w][prow][16 + lrow] = f2h(e1);
            Pl[w][prow][32 + lrow] = f2h(e2);
            Pl[w][prow][48 + lrow] = f2h(e3);
            Pl[w][prow][64 + lrow] = f2h(e4);
        }

        // ---- O = P V ----
        f32x4 o[4];
#pragma unroll
        for (int i = 0; i < 4; ++i)
#pragma unroll
            for (int e2 = 0; e2 < 4; ++e2) o[i][e2] = 0.f;
#pragma unroll
        for (int kk = 0; kk < 3; ++kk) {
            f16x8 pa = *(const f16x8*)&Pl[w][lrow][kk * 32 + lk * 8];
#pragma unroll
            for (int ctd = 0; ctd < 4; ++ctd) {
                f16x8 vf = *(const f16x8*)&Vs[(ctd * 16 + lrow) * 128 + (((kk * 4 + lk) ^ kswz) * 8)];
                o[ctd] = __builtin_amdgcn_mfma_f32_16x16x32_f16(pa, vf, o[ctd], 0, 0, 0);
            }
        }

        // ---- epilogue: deferred normalization + AO write ----
        const size_t rw = row0 + mt * 16 + lk * 4;
#pragma unroll
        for (int ctd = 0; ctd < 4; ++ctd)
#pragma unroll
            for (int r = 0; r < 4; ++r)
                AO[(rw + r) * 512 + h * 64 + ctd * 16 + lrow] = f2h(o[ctd][r] * rinv[r]);
    }
}

// ---------------------------------------------------------------------------
extern "C" void kernel_launch(void* const* d_in, const int* in_sizes, int n_in,
                              void* d_out, int out_size, void* d_ws, size_t ws_size,
                              hipStream_t stream)
{
    (void)in_sizes; (void)n_in; (void)out_size; (void)ws_size;
    const float* x    = (const float*)d_in[0];
    const float* cond = (const float*)d_in[1];
    const float* Wq   = (const float*)d_in[2];
    const float* Wk   = (const float*)d_in[3];
    const float* Wv   = (const float*)d_in[4];
    const float* Wo   = (const float*)d_in[5];
    const float* bo   = (const float*)d_in[6];

    char* ws = (char*)d_ws;
    _Float16* WqT  = (_Float16*)(ws);                        // 524288
    _Float16* WoT  = (_Float16*)(ws + 524288);               // 524288
    _Float16* Kswz = (_Float16*)(ws + 1048576);              // 128*96*64*2  = 1572864
    _Float16* Vswz = (_Float16*)(ws + 2621440);              // 128*64*128*2 = 2097152
    _Float16* xh   = (_Float16*)(ws + 4718592);              // 67108864 (ws end 71827456)
    // WkT/WvT alias the head of xh: dead before convert overwrites (stream order)
    _Float16* WkT  = (_Float16*)(ws + 4718592);              // 786432
    _Float16* WvT  = (_Float16*)(ws + 4718592 + 786432);     // 786432
    _Float16* AO   = xh;                                     // xh dead after gemm<0>
    _Float16* Qf   = (_Float16*)d_out;                       // f16 Q in d_out low half
                                                             // (fully dead before gemm<1>)

    prep<<<dim3(16, 24, 4), 256, 0, stream>>>(Wq, Wk, Wv, Wo, WqT, WkT, WvT, WoT);
    kv_proj<<<dim3(8, 16, 2), 256, 0, stream>>>(cond, WkT, WvT, Kswz, Vswz);
    convert<<<dim3(2048), 256, 0, stream>>>((const float4*)x, (f16x8*)xh, 16 * 4096 * 512 / 8);
    gemm512<0><<<dim3(2048), 256, 0, stream>>>(xh, WqT, Qf, nullptr);
    attn<<<dim3(16, 8, 16), 256, 0, stream>>>(Qf, Kswz, Vswz, AO);
    gemm512<1><<<dim3(2048), 256, 0, stream>>>(AO, WoT, d_out, bo);
}